// Round 5
// baseline (207.923 us; speedup 1.0000x reference)
//
#include <hip/hip_runtime.h>
#include <hip/hip_fp16.h>

typedef float    f32x4 __attribute__((ext_vector_type(4)));
typedef _Float16 f16x2 __attribute__((ext_vector_type(2)));
typedef _Float16 f16x4 __attribute__((ext_vector_type(4)));
typedef _Float16 f16x8 __attribute__((ext_vector_type(8)));

#define BS 8
#define NN 2048
#define DK 128
#define DM 64
#define MIXOFF (1024 * DK)  // halfs between mix-0 and mix-1 rows of one batch
// log2(e) / sqrt(128): folds softmax temperature AND exp->exp2 conversion into Q
#define QSCALE 0.12751744116926208f

#define MFMA32(a, b, c) __builtin_amdgcn_mfma_f32_16x16x32_f16((a), (b), (c), 0, 0, 0)
#define EXP2(x) __builtin_amdgcn_exp2f(x)

__device__ __forceinline__ f16x2 pkrtz(float x, float y) {
  return __builtin_bit_cast(f16x2, __builtin_amdgcn_cvt_pkrtz(x, y));
}

// async global->LDS DMA, 16B per lane; no VGPR transit (allocator-proof)
__device__ __forceinline__ void load_lds16(const _Float16* g, _Float16* l) {
  __builtin_amdgcn_global_load_lds(
      (const __attribute__((address_space(1))) void*)(uintptr_t)g,
      (__attribute__((address_space(3))) void*)(uint32_t)(uintptr_t)l, 16, 0, 0);
}

// ---- fused prep: K f32->f16 (512 blk), V transpose 64x64 (512 blk), q-mean (64 blk) ----
__global__ void prep_k(const float* __restrict__ kt, _Float16* __restrict__ kh,
                       const float* __restrict__ vt, _Float16* __restrict__ vT,
                       const float* __restrict__ qt, float* __restrict__ qpart) {
  __shared__ float tile[64][65];
  __shared__ float red[256];
  int blk = blockIdx.x;
  int t = threadIdx.x;
  if (blk < 512) {
    size_t base = (size_t)blk * 4096;
#pragma unroll
    for (int j = 0; j < 4; ++j) {
      size_t i = base + j * 1024 + t * 4;
      f32x4 v = *(const f32x4*)(kt + i);
      f16x4 h;
      h[0] = (_Float16)v[0]; h[1] = (_Float16)v[1];
      h[2] = (_Float16)v[2]; h[3] = (_Float16)v[3];
      *(f16x4*)(kh + i) = h;
    }
  } else if (blk < 1024) {
    int i2 = blk - 512;
    int b = i2 >> 6;
    int rem = i2 & 63;
    int j0 = (rem & 31) * 64;   // key tile
    int c0 = (rem >> 5) * 64;   // channel tile
    int tx = t & 63, ty = t >> 6;
    const float* src = vt + ((size_t)b * NN + j0) * DK + c0;
#pragma unroll
    for (int rr = 0; rr < 16; ++rr) {
      int row = ty * 16 + rr;
      tile[row][tx] = src[(size_t)row * DK + tx];
    }
    __syncthreads();
    _Float16* dst = vT + ((size_t)b * DK + c0) * NN + j0;
    int chl = t >> 4;
    int k4 = (t & 15) * 4;
#pragma unroll
    for (int r2 = 0; r2 < 4; ++r2) {
      int ch = r2 * 16 + chl;
      f16x4 h;
      h[0] = (_Float16)tile[k4 + 0][ch]; h[1] = (_Float16)tile[k4 + 1][ch];
      h[2] = (_Float16)tile[k4 + 2][ch]; h[3] = (_Float16)tile[k4 + 3][ch];
      *(f16x4*)(dst + (size_t)ch * NN + k4) = h;
    }
  } else {
    int i = blk - 1024;
    int b = i >> 3, seg = i & 7;
    int c = t & 127, h = t >> 7;
    const float* p = qt + ((size_t)b * NN + seg * 256 + h * 128) * DK + c;
    float s = 0.f;
#pragma unroll 8
    for (int n = 0; n < 128; ++n) s += p[(size_t)n * DK];
    red[t] = s;
    __syncthreads();
    if (t < 128) qpart[(size_t)i * 128 + t] = red[t] + red[t + 128];
  }
}

// Stage step S: K ONLY (both kh halves, 2 x 8KB = 16KB) into buffer BUF.
// 1024 16B units, 512 threads x 2. Same per-unit K map as R12/R14 (verified).
#define STAGE(BUF, S) do {                                                 \
    _Float16* db_ = stg + (BUF) * 8192;                                    \
    load_lds16(khg + gKst + (S) * 2048,          db_ + t * 8);             \
    load_lds16(khg + gKst + 65536 + (S) * 2048,  db_ + 4096 + t * 8);      \
  } while (0)

// ---------------- main: mixture flash attention -------------------------------
// grid 512 x 512thr (2 independent blk/CU, 4 waves/SIMD): b=blk&7, qb=blk>>3
// (32 q rows/block). R15/R16: V comes DIRECT FROM GLOBAL (L1/L2-resident), K
// stays LDS-staged. Rationale from R12-R14 counters: every structure kept V in
// LDS, which forced 8/12 of ds_reads, half the DMA, and >=64KB LDS (1 blk/CU,
// lockstep barrier -> 55% idle; R14 proved lockstep TLP doesn't help).
// V-frag from global needs NO swizzle: lane(l16,quad) reads 16B at
// vT[b][cc*16+l16][kh*1024 + s*32 + quad*8] — matches pw's k-slots exactly
// (lane's 8 scores = keys quad*8..+7, verified R0 mapping). Per wave per step:
// 4 K ds_reads : 12 MFMA (ratio 3), 8 vf global loads issued right after the
// barrier so QK+exp2 hides their L1/L2 latency. LDS 40KB -> two co-resident
// blocks with INDEPENDENT barriers fill each other's stalls (the TLP mechanism
// R14's single-barrier design lacked). Merges stay in LDS (R11 lesson).
// (R16 = R15 resubmitted verbatim: container failed twice = infra flake, the
// kernel was never measured; OOB/LDS/barrier audit found no defect.)
__global__ __launch_bounds__(512, 4) void attn_k(const float* __restrict__ qt,
                                                 const _Float16* __restrict__ khg,
                                                 const _Float16* __restrict__ vTg,
                                                 const float* __restrict__ kern,
                                                 const float* __restrict__ qpart,
                                                 float* __restrict__ out) {
  __shared__ __align__(16) char smem[40960];
  _Float16* stg = (_Float16*)smem;  // [2][8192] halfs = 2 x 16KB K staging
  const int b = blockIdx.x & 7;
  const int qb = blockIdx.x >> 3;   // 0..63, 32 q rows each
  const int t = threadIdx.x;
  const int wv = t >> 6;
  const int m = wv >> 2;        // mixture
  const int kh = (wv >> 1) & 1; // key half (in-block split-K)
  const int u = wv & 1;         // 16-query tile
  const int lane = t & 63;
  const int quad = lane >> 4, l16 = lane & 15;
  const int perm = ((l16 >> 2) << 3) | (l16 & 3);
  const int bq = b * (NN * DK);
  const int bV = b * (DK * NN);

  // Q fragment: 16 q rows x 2 chunks, f32 load + scale + pack in-register
  f16x8 qf[2];
#pragma unroll
  for (int c = 0; c < 2; ++c) {
    const float* qp_ = qt + bq + m * MIXOFF +
                       (qb * 32 + u * 16 + l16) * DM + quad * 8 + c * 32;
    f32x4 v0 = *(const f32x4*)qp_;
    f32x4 v1 = *(const f32x4*)(qp_ + 4);
    union { f16x8 v; f16x2 h[4]; } w;
    w.h[0] = pkrtz(v0[0] * QSCALE, v0[1] * QSCALE);
    w.h[1] = pkrtz(v0[2] * QSCALE, v0[3] * QSCALE);
    w.h[2] = pkrtz(v1[0] * QSCALE, v1[1] * QSCALE);
    w.h[3] = pkrtz(v1[2] * QSCALE, v1[3] * QSCALE);
    qf[c] = w.v;
  }

  // K staging offsets (halfs): thread t stages unit t of each kh region
  const int mixu = t >> 8;
  const int qq8 = t & 255;
  const int rK = qq8 >> 3;
  const int uuK = (qq8 & 7) ^ ((rK & 3) ^ (((rK >> 3) & 1) << 2));  // R12 swizzle
  const int gKst = bq + mixu * MIXOFF + rK * 64 + uuK * 8;

  // K LDS read offsets (halfs); R12 conflict-free pair
  const int gK = (l16 & 3) ^ (((l16 >> 2) & 1) << 2);
  const int kA = (quad ^ gK) * 8;
  const int kB = ((quad + 4) ^ gK) * 8;
  const int kbase = kh * 4096 + m * 2048 + perm * 64;

  // V global base: lane reads vT[b][cc*16+l16][kh*1024 + s*32 + quad*8]
  const _Float16* vpb = vTg + (size_t)bV + (size_t)l16 * NN + kh * 1024 + quad * 8;

  const f32x4 z = {0.f, 0.f, 0.f, 0.f};
  f32x4 acc[8];
  float lsum = 0.f;
#pragma unroll
  for (int cc = 0; cc < 8; ++cc) acc[cc] = z;

  STAGE(0, 0);
  int buf = 0;
  for (int s = 0; s < 32; ++s) {
    __syncthreads();  // K tile for step s landed; reads of buf^1 done
    if (s + 1 < 32) STAGE(buf ^ 1, s + 1);
    // issue V loads early: independent of QK chain, latency hidden under it
    f16x8 vf[8];
#pragma unroll
    for (int cc = 0; cc < 8; ++cc)
      vf[cc] = *(const f16x8*)(vpb + (size_t)cc * 16 * NN + s * 32);
    const _Float16* kb_ = stg + buf * 8192 + kbase;
    f16x8 kf0 = *(const f16x8*)(kb_ + kA);
    f16x8 kf1 = *(const f16x8*)(kb_ + kB);
    f16x8 kf2 = *(const f16x8*)(kb_ + 256 + kA);
    f16x8 kf3 = *(const f16x8*)(kb_ + 256 + kB);
    f32x4 s0 = MFMA32(kf1, qf[1], MFMA32(kf0, qf[0], z));
    f32x4 s1 = MFMA32(kf3, qf[1], MFMA32(kf2, qf[0], z));
    float e0 = EXP2(s0[0]), e1 = EXP2(s0[1]), e2 = EXP2(s0[2]), e3 = EXP2(s0[3]);
    float e4 = EXP2(s1[0]), e5 = EXP2(s1[1]), e6 = EXP2(s1[2]), e7 = EXP2(s1[3]);
    lsum += ((e0 + e1) + (e2 + e3)) + ((e4 + e5) + (e6 + e7));
    union { f16x8 v; f16x2 h[4]; } w;
    w.h[0] = pkrtz(e0, e1); w.h[1] = pkrtz(e2, e3);
    w.h[2] = pkrtz(e4, e5); w.h[3] = pkrtz(e6, e7);
#pragma unroll
    for (int cc = 0; cc < 8; ++cc) acc[cc] = MFMA32(vf[cc], w.v, acc[cc]);
    buf ^= 1;
  }
  __syncthreads();  // all K-tile reads done; epilogue overlays staging LDS

  // ---- epilogue LDS overlay ----
  float* obuf0 = (float*)smem;                 // [32][132] floats (16896 B), m=0
  float* obuf1 = (float*)(smem + 16896);       // [32][132] floats, m=1
  float* barL = (float*)(smem + 33792);        // [8][128]
  float* lgp = (float*)(smem + 37888);
  float* exq = (float*)(smem + 37952);
  float* prp = (float*)(smem + 38016);
  float* lbuf = (float*)(smem + 38080);        // [4][32]: per-(m,kh) l partials

  // l: reduce across quads, publish per-wave partials
  lsum += __shfl_xor(lsum, 16);
  lsum += __shfl_xor(lsum, 32);
  // prior softmax inputs (redundant per block)
  for (int e = t; e < 1024; e += 512) {
    int bb = e >> 7, c = e & 127;
    float ss = 0.f;
#pragma unroll
    for (int seg = 0; seg < 8; ++seg) ss += qpart[(size_t)(bb * 8 + seg) * 128 + c];
    barL[e] = ss * (1.0f / 2048.0f);
  }
  if (quad == 0) lbuf[(m * 2 + kh) * 32 + u * 16 + l16] = lsum;
  __syncthreads();
  if (t < 16) {
    int mm = t >> 3, bb = t & 7;
    float ss = 0.f;
    for (int c = 0; c < DK; ++c) ss += kern[mm * DK + c] * barL[bb * 128 + c];
    lgp[t] = ss;
  }
  __syncthreads();
  if (t < 16) {
    int mm = t >> 3;
    float mx = lgp[mm * 8];
    for (int i2 = 1; i2 < 8; ++i2) mx = fmaxf(mx, lgp[mm * 8 + i2]);
    exq[t] = __expf(lgp[t] - mx);
  }
  __syncthreads();
  if (t < 16) {
    int mm = t >> 3;
    float sm = 0.f;
    for (int i2 = 0; i2 < 8; ++i2) sm += exq[mm * 8 + i2];
    prp[t] = exq[t] / sm;  // flat[m*8+b]; read as [b*2+m] (TF reshape quirk)
  }
  __syncthreads();

  const float wm = prp[b * 2 + m];
  const int q = u * 16 + l16;
  const float rr = wm / (lbuf[(m * 2 + 0) * 32 + q] + lbuf[(m * 2 + 1) * 32 + q]);

  // ---- 2-phase split-K merge over kh; m=0/m=1 parallel on separate obufs ----
  float* ob = (m == 0) ? obuf0 : obuf1;
  if (kh == 0) {  // seed with scaled acc
    int r_ = q * 132 + quad * 4;
#pragma unroll
    for (int cc = 0; cc < 8; ++cc) {
      f32x4 o;
#pragma unroll
      for (int e = 0; e < 4; ++e) o[e] = acc[cc][e] * rr;
      *(f32x4*)&ob[r_ + cc * 16] = o;
    }
  }
  __syncthreads();
  if (kh == 1) {
    int r_ = q * 132 + quad * 4;
#pragma unroll
    for (int cc = 0; cc < 8; ++cc) {
      f32x4 o = *(const f32x4*)&ob[r_ + cc * 16];
#pragma unroll
      for (int e = 0; e < 4; ++e) o[e] += acc[cc][e] * rr;
      *(f32x4*)&ob[r_ + cc * 16] = o;
    }
  }
  __syncthreads();

  const int row = t >> 4;        // 0..31
  const int cb = (t & 15) * 8;   // 0..120
  float* op = out + ((size_t)b * NN + qb * 32 + row) * DK + cb;
#pragma unroll
  for (int g = 0; g < 2; ++g) {
    f32x4 a = *(const f32x4*)&obuf0[row * 132 + cb + g * 4];
    f32x4 c = *(const f32x4*)&obuf1[row * 132 + cb + g * 4];
#pragma unroll
    for (int e = 0; e < 4; ++e) a[e] += c[e];
    *(f32x4*)(op + g * 4) = a;
  }
}

extern "C" void kernel_launch(void* const* d_in, const int* in_sizes, int n_in,
                              void* d_out, int out_size, void* d_ws, size_t ws_size,
                              hipStream_t stream) {
  const float* qt = (const float*)d_in[0];
  const float* kt = (const float*)d_in[1];
  const float* vt = (const float*)d_in[2];
  const float* kern = (const float*)d_in[3];
  float* out = (float*)d_out;

  char* ws = (char*)d_ws;
  float* qpart = (float*)(ws + 4096);         // 64*128 floats (32 KB)
  _Float16* khp = (_Float16*)(ws + 65536);    // 2M halfs (4 MB)
  _Float16* vTp = khp + (size_t)BS * NN * DK; // 2M halfs (4 MB)

  prep_k<<<dim3(1088), dim3(256), 0, stream>>>(kt, khp, vt, vTp, qt, qpart);
  attn_k<<<dim3(512), dim3(512), 0, stream>>>(qt, khp, vTp, kern, qpart, out);
}

// Round 6
// 131.588 us; speedup vs baseline: 1.5801x; 1.5801x over previous
//
#include <hip/hip_runtime.h>
#include <hip/hip_fp16.h>

typedef float    f32x4 __attribute__((ext_vector_type(4)));
typedef _Float16 f16x2 __attribute__((ext_vector_type(2)));
typedef _Float16 f16x4 __attribute__((ext_vector_type(4)));
typedef _Float16 f16x8 __attribute__((ext_vector_type(8)));

#define BS 8
#define NN 2048
#define DK 128
#define DM 64
#define MIXOFF (1024 * DK)  // halfs between mix-0 and mix-1 rows of one batch
// log2(e) / sqrt(128): folds softmax temperature AND exp->exp2 conversion into Q
#define QSCALE 0.12751744116926208f

#define MFMA32(a, b, c) __builtin_amdgcn_mfma_f32_16x16x32_f16((a), (b), (c), 0, 0, 0)
#define EXP2(x) __builtin_amdgcn_exp2f(x)

__device__ __forceinline__ f16x2 pkrtz(float x, float y) {
  return __builtin_bit_cast(f16x2, __builtin_amdgcn_cvt_pkrtz(x, y));
}

// async global->LDS DMA, 16B per lane; no VGPR transit (allocator-proof)
__device__ __forceinline__ void load_lds16(const _Float16* g, _Float16* l) {
  __builtin_amdgcn_global_load_lds(
      (const __attribute__((address_space(1))) void*)(uintptr_t)g,
      (__attribute__((address_space(3))) void*)(uint32_t)(uintptr_t)l, 16, 0, 0);
}

// ---- fused prep: K f32->f16 (512 blk), V transpose 64x64 (512 blk), q-mean (64 blk) ----
__global__ void prep_k(const float* __restrict__ kt, _Float16* __restrict__ kh,
                       const float* __restrict__ vt, _Float16* __restrict__ vT,
                       const float* __restrict__ qt, float* __restrict__ qpart) {
  __shared__ float tile[64][65];
  __shared__ float red[256];
  int blk = blockIdx.x;
  int t = threadIdx.x;
  if (blk < 512) {
    size_t base = (size_t)blk * 4096;
#pragma unroll
    for (int j = 0; j < 4; ++j) {
      size_t i = base + j * 1024 + t * 4;
      f32x4 v = *(const f32x4*)(kt + i);
      f16x4 h;
      h[0] = (_Float16)v[0]; h[1] = (_Float16)v[1];
      h[2] = (_Float16)v[2]; h[3] = (_Float16)v[3];
      *(f16x4*)(kh + i) = h;
    }
  } else if (blk < 1024) {
    int i2 = blk - 512;
    int b = i2 >> 6;
    int rem = i2 & 63;
    int j0 = (rem & 31) * 64;   // key tile
    int c0 = (rem >> 5) * 64;   // channel tile
    int tx = t & 63, ty = t >> 6;
    const float* src = vt + ((size_t)b * NN + j0) * DK + c0;
#pragma unroll
    for (int rr = 0; rr < 16; ++rr) {
      int row = ty * 16 + rr;
      tile[row][tx] = src[(size_t)row * DK + tx];
    }
    __syncthreads();
    _Float16* dst = vT + ((size_t)b * DK + c0) * NN + j0;
    int chl = t >> 4;
    int k4 = (t & 15) * 4;
#pragma unroll
    for (int r2 = 0; r2 < 4; ++r2) {
      int ch = r2 * 16 + chl;
      f16x4 h;
      h[0] = (_Float16)tile[k4 + 0][ch]; h[1] = (_Float16)tile[k4 + 1][ch];
      h[2] = (_Float16)tile[k4 + 2][ch]; h[3] = (_Float16)tile[k4 + 3][ch];
      *(f16x4*)(dst + (size_t)ch * NN + k4) = h;
    }
  } else {
    int i = blk - 1024;
    int b = i >> 3, seg = i & 7;
    int c = t & 127, h = t >> 7;
    const float* p = qt + ((size_t)b * NN + seg * 256 + h * 128) * DK + c;
    float s = 0.f;
#pragma unroll 8
    for (int n = 0; n < 128; ++n) s += p[(size_t)n * DK];
    red[t] = s;
    __syncthreads();
    if (t < 128) qpart[(size_t)i * 128 + t] = red[t] + red[t + 128];
  }
}

// Stage step S for this block's key range: 64 keys as 2 hh-chunks of 32.
// K: [hh][m][2048 halfs swizzled] (8KB), V: [hh][128ch][32key swizzled] (8KB)
// wait: K = 2hh x 4KB = 8KB? K per hh = 2m x 32key x 64ch x 2B = 8KB -> 16KB K,
// V per hh = 32key x 128ch x 2B = 8KB -> 16KB V. 32KB/step total. 4096 16B
// units, 512 threads x 4. Per-unit maps verbatim from R12 (verified).
#define STAGE(BUF, S) do {                                                  \
    _Float16* db_ = stg + (BUF) * 16384;                                    \
    load_lds16(khg + gKst + (S) * 4096,        db_ + t * 8);                \
    load_lds16(khg + gKst + (S) * 4096 + 2048, db_ + 4096 + t * 8);         \
    load_lds16(vTg + gVst + (S) * 64,          db_ + 8192 + t * 8);         \
    load_lds16(vTg + gVst + (S) * 64 + 32,     db_ + 12288 + t * 8);        \
  } while (0)

// ---------------- main: mixture flash attention, cross-block split-K ----------
// R17: the R0/R12 plateau (43-51us for every schedule) is DMA-bound: each block
// streamed the full 1MB K+V of its batch from L3 (K+V 8MB > 4MB/XCD L2), and
// per-CU L3->LDS fill caps ~10B/cy -> 1MB = ~44us regardless of ratio/TLP.
// Only lever: fewer staged bytes per block. Grid 256 = b(8) x qb(16: 128q) x
// kb(2: 1024 keys) -> 512KB/block. Waves = (m,u): 32q/wave, ALL block keys,
// NO in-block split-K -> acc/lsum are complete partials for [kb*1024,+1024);
// epilogue = pure global stores of unnormalized O-planes + l partials (no LDS
// phases at all). merge_k combines (separate streaming kernel, NOT R11's
// in-kernel global-slot sync). Staging/read maps verbatim R12-verified, with
// 64 keys/step as two 32-key hh chunks; 16 steps x 32KB, dbuf 64KB.
__global__ __launch_bounds__(512, 2) void attn_k(const float* __restrict__ qt,
                                                 const _Float16* __restrict__ khg,
                                                 const _Float16* __restrict__ vTg,
                                                 float* __restrict__ opart,
                                                 float* __restrict__ lpart) {
  __shared__ __align__(16) char smem[65536];
  _Float16* stg = (_Float16*)smem;  // [2][16384] halfs = 2 x 32KB staging
  const int b = blockIdx.x & 7;
  const int qb = (blockIdx.x >> 3) & 15;  // 128-q tile
  const int kb = blockIdx.x >> 7;         // 1024-key half
  const int t = threadIdx.x;
  const int wv = t >> 6;
  const int m = wv >> 2;        // mixture
  const int u = wv & 3;         // 32-query tile within the 128
  const int lane = t & 63;
  const int quad = lane >> 4, l16 = lane & 15;
  const int perm = ((l16 >> 2) << 3) | (l16 & 3);
  const int bq = b * (NN * DK);
  const int bV = b * (DK * NN);

  // Q fragments: 2 subtiles x 2 chunks, f32 load + scale + pack in-register
  f16x8 qf[2][2];  // [su][chunk]
#pragma unroll
  for (int su = 0; su < 2; ++su)
#pragma unroll
    for (int c = 0; c < 2; ++c) {
      const float* qp_ = qt + bq + m * MIXOFF +
                         (qb * 128 + u * 32 + su * 16 + l16) * DM + quad * 8 + c * 32;
      f32x4 v0 = *(const f32x4*)qp_;
      f32x4 v1 = *(const f32x4*)(qp_ + 4);
      union { f16x8 v; f16x2 h[4]; } w;
      w.h[0] = pkrtz(v0[0] * QSCALE, v0[1] * QSCALE);
      w.h[1] = pkrtz(v0[2] * QSCALE, v0[3] * QSCALE);
      w.h[2] = pkrtz(v1[0] * QSCALE, v1[1] * QSCALE);
      w.h[3] = pkrtz(v1[2] * QSCALE, v1[3] * QSCALE);
      qf[su][c] = w.v;
    }

  // staging offsets (halfs): thread t stages unit t of each region (R12 maps)
  const int mixu = t >> 8;
  const int qq8 = t & 255;
  const int rK = qq8 >> 3;
  const int uuK = (qq8 & 7) ^ ((rK & 3) ^ (((rK >> 3) & 1) << 2));  // R12 swizzle
  const int chV = t >> 2;
  const int uuV = (t & 3) ^ ((chV + (chV >> 2)) & 3);
  const int gKst = bq + mixu * MIXOFF + kb * 65536 + rK * 64 + uuK * 8;
  const int gVst = bV + chV * NN + kb * 1024 + uuV * 8;

  // LDS read offsets (halfs); R12 conflict-free maps
  const int gK = (l16 & 3) ^ (((l16 >> 2) & 1) << 2);
  const int hV = (l16 + (l16 >> 2)) & 3;
  const int kA = (quad ^ gK) * 8;
  const int kB = ((quad + 4) ^ gK) * 8;
  const int kbase = m * 2048 + perm * 64;
  const int vboff = l16 * 32 + (quad ^ hV) * 8;

  const f32x4 z = {0.f, 0.f, 0.f, 0.f};
  f32x4 acc[2][8];  // [su][cc]
  float lsum[2] = {0.f, 0.f};
#pragma unroll
  for (int su = 0; su < 2; ++su)
#pragma unroll
    for (int cc = 0; cc < 8; ++cc) acc[su][cc] = z;

  STAGE(0, 0);
  int buf = 0;
  for (int s = 0; s < 16; ++s) {
    __syncthreads();  // tiles for step s landed; reads of buf^1 done
    if (s + 1 < 16) STAGE(buf ^ 1, s + 1);
    const _Float16* sb_ = stg + buf * 16384;
#pragma unroll
    for (int hh = 0; hh < 2; ++hh) {
      const _Float16* kp_ = sb_ + hh * 4096 + kbase;
      f16x8 kf0 = *(const f16x8*)(kp_ + kA);
      f16x8 kf1 = *(const f16x8*)(kp_ + kB);
      f16x8 kf2 = *(const f16x8*)(kp_ + 256 + kA);
      f16x8 kf3 = *(const f16x8*)(kp_ + 256 + kB);
      f16x8 pw[2];
#pragma unroll
      for (int su = 0; su < 2; ++su) {
        f32x4 s0 = MFMA32(kf1, qf[su][1], MFMA32(kf0, qf[su][0], z));
        f32x4 s1 = MFMA32(kf3, qf[su][1], MFMA32(kf2, qf[su][0], z));
        float e0 = EXP2(s0[0]), e1 = EXP2(s0[1]), e2 = EXP2(s0[2]), e3 = EXP2(s0[3]);
        float e4 = EXP2(s1[0]), e5 = EXP2(s1[1]), e6 = EXP2(s1[2]), e7 = EXP2(s1[3]);
        lsum[su] += ((e0 + e1) + (e2 + e3)) + ((e4 + e5) + (e6 + e7));
        union { f16x8 v; f16x2 h[4]; } w;
        w.h[0] = pkrtz(e0, e1); w.h[1] = pkrtz(e2, e3);
        w.h[2] = pkrtz(e4, e5); w.h[3] = pkrtz(e6, e7);
        pw[su] = w.v;
      }
      const _Float16* vb_ = sb_ + 8192 + hh * 4096 + vboff;
      f16x8 vf[8];
#pragma unroll
      for (int cc = 0; cc < 8; ++cc) vf[cc] = *(const f16x8*)(vb_ + cc * 512);
#pragma unroll
      for (int cc = 0; cc < 8; ++cc)
#pragma unroll
        for (int su = 0; su < 2; ++su) acc[su][cc] = MFMA32(vf[cc], pw[su], acc[su][cc]);
    }
    buf ^= 1;
  }

  // ---- epilogue: pure global stores of split-K partials (no LDS phases) ----
#pragma unroll
  for (int su = 0; su < 2; ++su) {
    lsum[su] += __shfl_xor(lsum[su], 16);
    lsum[su] += __shfl_xor(lsum[su], 32);
  }
  const size_t plane = (size_t)((b * 2 + kb) * 2 + m);
#pragma unroll
  for (int su = 0; su < 2; ++su) {
    const int qg = qb * 128 + u * 32 + su * 16 + l16;
    if (quad == 0) lpart[plane * 2048 + qg] = lsum[su];
    float* op = opart + (plane * 2048 + qg) * (size_t)128 + quad * 4;
#pragma unroll
    for (int cc = 0; cc < 8; ++cc) *(f32x4*)(op + cc * 16) = acc[su][cc];
  }
}

// ---- merge: prior softmax (verbatim logic) + cross-block split-K combine ----
// out[b][q][d] = sum_m prp[b*2+m] * (Op[b,kb0,m,q,d]+Op[b,kb1,m,q,d])
//                                  / (lp[b,kb0,m,q]+lp[b,kb1,m,q])
__global__ __launch_bounds__(256) void merge_k(const float* __restrict__ qpart,
                                               const float* __restrict__ kern,
                                               const float* __restrict__ opart,
                                               const float* __restrict__ lpart,
                                               float* __restrict__ out) {
  __shared__ float barL[1024];
  __shared__ float lgp[16], exq[16], prp[16];
  const int t = threadIdx.x;
  const int b = blockIdx.x & 7;
  const int qc = blockIdx.x >> 3;  // 0..31, 64 q rows each
  for (int e = t; e < 1024; e += 256) {
    int bb = e >> 7, c = e & 127;
    float ss = 0.f;
#pragma unroll
    for (int seg = 0; seg < 8; ++seg) ss += qpart[(size_t)(bb * 8 + seg) * 128 + c];
    barL[e] = ss * (1.0f / 2048.0f);
  }
  __syncthreads();
  if (t < 16) {
    int mm = t >> 3, bb = t & 7;
    float ss = 0.f;
    for (int c = 0; c < DK; ++c) ss += kern[mm * DK + c] * barL[bb * 128 + c];
    lgp[t] = ss;
  }
  __syncthreads();
  if (t < 16) {
    int mm = t >> 3;
    float mx = lgp[mm * 8];
    for (int i2 = 1; i2 < 8; ++i2) mx = fmaxf(mx, lgp[mm * 8 + i2]);
    exq[t] = __expf(lgp[t] - mx);
  }
  __syncthreads();
  if (t < 16) {
    int mm = t >> 3;
    float sm = 0.f;
    for (int i2 = 0; i2 < 8; ++i2) sm += exq[mm * 8 + i2];
    prp[t] = exq[t] / sm;  // flat[m*8+b]; read as [b*2+m] (TF reshape quirk)
  }
  __syncthreads();
  const float w0 = prp[b * 2 + 0], w1 = prp[b * 2 + 1];
  const int q = qc * 64 + (t >> 2);
  const int dc = (t & 3) * 32;
  const float l00 = lpart[((b * 2 + 0) * 2 + 0) * 2048 + q];  // kb0, m0
  const float l01 = lpart[((b * 2 + 0) * 2 + 1) * 2048 + q];  // kb0, m1
  const float l10 = lpart[((b * 2 + 1) * 2 + 0) * 2048 + q];  // kb1, m0
  const float l11 = lpart[((b * 2 + 1) * 2 + 1) * 2048 + q];  // kb1, m1
  const float r0 = w0 / (l00 + l10);
  const float r1 = w1 / (l01 + l11);
  const float* p00 = opart + ((size_t)(((b * 2 + 0) * 2 + 0) * 2048 + q)) * 128 + dc;
  const float* p01 = opart + ((size_t)(((b * 2 + 0) * 2 + 1) * 2048 + q)) * 128 + dc;
  const float* p10 = opart + ((size_t)(((b * 2 + 1) * 2 + 0) * 2048 + q)) * 128 + dc;
  const float* p11 = opart + ((size_t)(((b * 2 + 1) * 2 + 1) * 2048 + q)) * 128 + dc;
  float* po = out + ((size_t)b * NN + q) * DK + dc;
#pragma unroll
  for (int g = 0; g < 8; ++g) {
    f32x4 a0 = *(const f32x4*)(p00 + g * 4);
    f32x4 a1 = *(const f32x4*)(p01 + g * 4);
    f32x4 b0 = *(const f32x4*)(p10 + g * 4);
    f32x4 b1 = *(const f32x4*)(p11 + g * 4);
    f32x4 o;
#pragma unroll
    for (int e = 0; e < 4; ++e) o[e] = (a0[e] + b0[e]) * r0 + (a1[e] + b1[e]) * r1;
    *(f32x4*)(po + g * 4) = o;
  }
}

extern "C" void kernel_launch(void* const* d_in, const int* in_sizes, int n_in,
                              void* d_out, int out_size, void* d_ws, size_t ws_size,
                              hipStream_t stream) {
  const float* qt = (const float*)d_in[0];
  const float* kt = (const float*)d_in[1];
  const float* vt = (const float*)d_in[2];
  const float* kern = (const float*)d_in[3];
  float* out = (float*)d_out;

  char* ws = (char*)d_ws;
  float* qpart = (float*)(ws + 4096);          // 64*128 floats (32 KB)
  _Float16* khp = (_Float16*)(ws + 65536);     // 2M halfs (4 MB)
  _Float16* vTp = khp + (size_t)BS * NN * DK;  // 2M halfs (4 MB)
  float* opart = (float*)(ws + (16u << 20));   // [8b][2kb][2m][2048q][128d] f32 (32 MB)
  float* lpart = (float*)(ws + (48u << 20));   // [8b][2kb][2m][2048q] f32 (256 KB)

  prep_k<<<dim3(1088), dim3(256), 0, stream>>>(kt, khp, vt, vTp, qt, qpart);
  attn_k<<<dim3(256), dim3(512), 0, stream>>>(qt, khp, vTp, opart, lpart);
  merge_k<<<dim3(256), dim3(256), 0, stream>>>(qpart, kern, opart, lpart, out);
}